// Round 4
// baseline (408.239 us; speedup 1.0000x reference)
//
#include <hip/hip_runtime.h>

#define NN 100000
#define EE 3200000
#define NF 256
#define NH 128
#define NC 16
#define NBKT 391       // buckets of 256 dst nodes: ceil(100000/256)
#define BSZ 256        // nodes per bucket
#define BCAP 9600      // staging capacity per bucket (mean 8192, +15.5 sigma)
#define CHUNK 4096     // edges per k_bucket block

typedef __bf16 bf16;
typedef bf16 bf16x2 __attribute__((ext_vector_type(2)));
typedef bf16 bf16x4 __attribute__((ext_vector_type(4)));
typedef bf16 bf16x8 __attribute__((ext_vector_type(8)));
typedef float f32x2 __attribute__((ext_vector_type(2)));
typedef float f32x4 __attribute__((ext_vector_type(4)));

// ---------------- CSR build: bucket partition + per-bucket LDS sort ----------------

__global__ void k_init(int* __restrict__ bucket_cursor, int2* __restrict__ edges) {
    int t = threadIdx.x;
    if (t < NBKT) bucket_cursor[t] = t * BCAP;
    if (t >= 480) edges[EE + t - 480] = make_int2(0, 0);  // 32-record pad for spmm overrun
}

// Pass 1: partition edges into NBKT staging regions, LDS-binned so global
// writes are contiguous runs per bucket instead of 8B scatter.
__global__ __launch_bounds__(512) void k_bucket(const int* __restrict__ src,
                                                const int* __restrict__ dst,
                                                const float* __restrict__ ew,
                                                int* __restrict__ bucket_cursor,
                                                int2* __restrict__ staged) {
    __shared__ int2 recs[CHUNK];              // 32 KB
    __shared__ unsigned short bkt[CHUNK];     // 8 KB
    __shared__ int cnt[NBKT], start[NBKT + 1], cur[NBKT], gbase[NBKT];
    __shared__ int sc[512];
    int t = threadIdx.x;
    int base = blockIdx.x * CHUNK;
    int n = EE - base; if (n > CHUNK) n = CHUNK;
    if (t < NBKT) cnt[t] = 0;
    __syncthreads();
    for (int i = t; i < n; i += 512) {
        atomicAdd(&cnt[dst[base + i] >> 8], 1);
    }
    __syncthreads();
    sc[t] = (t < NBKT) ? cnt[t] : 0;
    __syncthreads();
    for (int off = 1; off < 512; off <<= 1) {
        int v = (t >= off) ? sc[t - off] : 0;
        __syncthreads();
        sc[t] += v;
        __syncthreads();
    }
    if (t < NBKT) { start[t] = sc[t] - cnt[t]; cur[t] = sc[t] - cnt[t]; }
    if (t == 0) start[NBKT] = sc[511];
    __syncthreads();
    for (int i = t; i < n; i += 512) {
        int d = dst[base + i];
        int b = d >> 8;
        int p = atomicAdd(&cur[b], 1);
        recs[p] = make_int2(src[base + i] | ((d & 255) << 17), __float_as_int(ew[base + i]));
        bkt[p] = (unsigned short)b;
    }
    __syncthreads();
    if (t < NBKT) gbase[t] = atomicAdd(&bucket_cursor[t], start[t + 1] - start[t]);
    __syncthreads();
    for (int i = t; i < n; i += 512) {
        int b = bkt[i];
        staged[gbase[b] + (i - start[b])] = recs[i];
    }
}

// Exclusive scan of per-bucket counts -> global base of each bucket in edges[].
__global__ void k_bscan(const int* __restrict__ bucket_cursor,
                        int* __restrict__ bucket_base, int* __restrict__ row_off) {
    __shared__ int s[512];
    int t = threadIdx.x;
    int v = (t < NBKT) ? (bucket_cursor[t] - t * BCAP) : 0;
    s[t] = v;
    __syncthreads();
    for (int off = 1; off < 512; off <<= 1) {
        int x = (t >= off) ? s[t - off] : 0;
        __syncthreads();
        s[t] += x;
        __syncthreads();
    }
    if (t < NBKT) bucket_base[t] = s[t] - v;
    if (t == 0) { bucket_base[NBKT] = EE; row_off[NN] = EE; }
}

// One block per bucket: LDS counting sort. 512 threads, 79.9 KB LDS ->
// 2 blocks/CU (16 waves), 391 blocks ~ one balanced round over 256 CUs.
__global__ __launch_bounds__(512) void k_sort(const int2* __restrict__ staged,
                                              const int* __restrict__ bucket_cursor,
                                              const int* __restrict__ bucket_base,
                                              int* __restrict__ row_off,
                                              int2* __restrict__ edges) {
    __shared__ int2 lrec[BCAP];               // 76.8 KB
    __shared__ int lcnt[BSZ], lstart[BSZ], lcur[BSZ];
    int t = threadIdx.x;
    int b = blockIdx.x;
    int n = bucket_cursor[b] - b * BCAP;
    int gb = bucket_base[b];
    const int2* sp = staged + (size_t)b * BCAP;
    if (t < BSZ) lcnt[t] = 0;
    __syncthreads();
    for (int i = t; i < n; i += 512) {
        int2 r = sp[i];
        lrec[i] = r;
        atomicAdd(&lcnt[r.x >> 17], 1);
    }
    __syncthreads();
    if (t < BSZ) lstart[t] = lcnt[t];
    __syncthreads();
    for (int off = 1; off < BSZ; off <<= 1) {
        int v = 0;
        if (t < BSZ && t >= off) v = lstart[t - off];
        __syncthreads();
        if (t < BSZ) lstart[t] += v;
        __syncthreads();
    }
    if (t < BSZ) {
        int ex = lstart[t] - lcnt[t];        // exclusive within-bucket start
        lcur[t] = ex;
        int node = (b << 8) + t;
        if (node < NN) row_off[node] = gb + ex;
    }
    __syncthreads();
    for (int i = t; i < n; i += 512) {
        int2 r = lrec[i];
        int d = r.x >> 17;
        int p = atomicAdd(&lcur[d], 1);
        edges[gb + p] = make_int2(r.x & 0x1FFFF, r.y);
    }
}

// ---------------- layer 1: x @ W1 (bf16 MFMA), h0 stored as FP8 e4m3 ----------------

__global__ void k_cvtW1(const float* __restrict__ W1, bf16* __restrict__ W1T) {
    int i = blockIdx.x * 256 + threadIdx.x;  // 32768 elems, W1 is [NF][NH]
    int k = i >> 7, n = i & 127;
    W1T[n * NF + k] = (bf16)W1[i];           // W1T: [NH][NF]
}

// v3: swapped MFMA operands -- D = W x^T, so each lane's 4 acc regs are 4
// CONSECUTIVE features of ONE x-row -> epilogue packs them into a single
// dword store (was 64 scattered byte stores). 512-thread blocks, 1 tile/wave
// (VGPR ~80) -> launch_bounds(512,4) holds, 2 blocks/CU = 16 waves/CU (2x
// occupancy of v2, which measured 16% and was latency-starved).
__global__ __launch_bounds__(512, 4) void k_gemm1(const float* __restrict__ x,
                                                  const bf16* __restrict__ W1T,
                                                  unsigned char* __restrict__ h0q) {
    __shared__ unsigned short sW[NH * NF];   // 64 KB
    int t = threadIdx.x;
    int lane = t & 63;
    int wid = t >> 6;      // 0..7
    int m = lane & 15;     // x row within 16-tile (B col) == A-frag row for W load
    int kg = lane >> 4;    // k-group 0..3
    int row = blockIdx.x * 128 + wid * 16 + m;
    bool in = (row < NN);
    const float* xr = x + (size_t)row * NF;

    // x loads first: 16 global loads in flight while LDS staging completes
    bf16x8 a[8];
#pragma unroll
    for (int kt = 0; kt < 8; kt++) {
        int k0 = kt * 32 + kg * 8;
        float4 u = in ? *(const float4*)(xr + k0)     : make_float4(0.f, 0.f, 0.f, 0.f);
        float4 v = in ? *(const float4*)(xr + k0 + 4) : make_float4(0.f, 0.f, 0.f, 0.f);
        bf16x8 av = { (bf16)u.x, (bf16)u.y, (bf16)u.z, (bf16)u.w,
                      (bf16)v.x, (bf16)v.y, (bf16)v.z, (bf16)v.w };
        a[kt] = av;
    }

    // stage W1T -> LDS: chunk c (16 B) of row n lands at chunk (c ^ (n&7))
    for (int cid = t; cid < NH * (NF / 8); cid += 512) {   // 4096 chunks
        int n = cid >> 5, ch = cid & 31;
        bf16x8 v = *(const bf16x8*)(W1T + (size_t)n * NF + ch * 8);
        *(bf16x8*)&sW[n * NF + ((ch ^ (n & 7)) << 3)] = v;
    }
    __syncthreads();

    f32x4 acc[8] = {};
#pragma unroll
    for (int ct = 0; ct < 8; ct++) {
        int brow = ct * 16 + m;                  // W feature row (A operand)
        const unsigned short* bp = sW + brow * NF;
        int sw = brow & 7;
#pragma unroll
        for (int kt = 0; kt < 8; kt++) {
            int ch = kt * 4 + kg;
            bf16x8 b = *(const bf16x8*)(bp + ((ch ^ sw) << 3));
            // A = W fragment, B = x fragment: D[feat][xrow]
            acc[ct] = __builtin_amdgcn_mfma_f32_16x16x32_bf16(b, a[kt], acc[ct], 0, 0, 0);
        }
    }

    // D layout: col = lane&15 = x row (this lane's own row), row = kg*4 + reg
    // = feature within ct-tile -> 4 consecutive features -> 1 dword fp8 store.
    if (in) {
        unsigned char* rp = h0q + (size_t)row * NH + kg * 4;
#pragma unroll
        for (int ct = 0; ct < 8; ct++) {
            unsigned lo = (unsigned)__builtin_amdgcn_cvt_pk_fp8_f32(
                              acc[ct][0], acc[ct][1], 0, false);
            unsigned pk = (unsigned)__builtin_amdgcn_cvt_pk_fp8_f32(
                              acc[ct][2], acc[ct][3], lo, true);
            *(unsigned*)(rp + ct * 16) = pk;
        }
    }
}

// ---------------- spmm1: h = relu(A @ h0 + b1) ----------------
// v4: 32 edges/iter -> 16 dword gathers in flight per wave (was 8). Half-wave
// pairing: lanes 0-31 take even edges, 32-63 odd; each lane gathers a dword
// (4 fp8 channels). Edge records on the scalar pipe; OOB -> src=0,w=0.

__global__ __launch_bounds__(256) void k_spmm1(const int* __restrict__ row_off,
                                               const int2* __restrict__ edges,
                                               const unsigned char* __restrict__ h0q,
                                               const float* __restrict__ b1,
                                               bf16* __restrict__ h) {
    int wid = __builtin_amdgcn_readfirstlane(threadIdx.x >> 6);
    int node = blockIdx.x * 4 + wid;               // wave-uniform, always < NN
    int lane = threadIdx.x & 63;
    int lq = lane & 31;
    bool hhi = lane >= 32;                         // loop-invariant half mask
    int s = row_off[node], e = row_off[node + 1];  // uniform -> s_load

    unsigned loff = (unsigned)lq * 4u;             // byte offset within row

    float a0[2] = {0.f, 0.f}, a1[2] = {0.f, 0.f};
    float a2[2] = {0.f, 0.f}, a3[2] = {0.f, 0.f};

    for (int i = s; i < e; i += 32) {
        int2 q[32];
#pragma unroll
        for (int j = 0; j < 32; j++) q[j] = edges[i + j];   // uniform -> s_load
        unsigned so[16]; float wo[16];
#pragma unroll
        for (int j = 0; j < 16; j++) {
            bool v0 = (i + 2 * j)     < e;                   // scalar cmp
            bool v1 = (i + 2 * j + 1) < e;
            unsigned s0 = v0 ? (unsigned)q[2 * j].x : 0u;    // s_cselect
            unsigned s1 = v1 ? (unsigned)q[2 * j + 1].x : 0u;
            float w0 = v0 ? __int_as_float(q[2 * j].y) : 0.f;
            float w1 = v1 ? __int_as_float(q[2 * j + 1].y) : 0.f;
            so[j] = hhi ? s1 : s0;                           // v_cndmask
            wo[j] = hhi ? w1 : w0;                           // v_cndmask
        }
        unsigned dv[16];
#pragma unroll
        for (int j = 0; j < 16; j++) {
            unsigned off = (so[j] << 7) + loff;              // 1 VALU, 24-bit range
            dv[j] = *(const unsigned*)(h0q + off);           // 16 gathers in flight
        }
#pragma unroll
        for (int j = 0; j < 16; j++) {
            f32x2 f01 = __builtin_amdgcn_cvt_pk_f32_fp8(dv[j], false);
            f32x2 f23 = __builtin_amdgcn_cvt_pk_f32_fp8(dv[j], true);
            int p = j & 1;
            a0[p] += wo[j] * f01[0];
            a1[p] += wo[j] * f01[1];
            a2[p] += wo[j] * f23[0];
            a3[p] += wo[j] * f23[1];
        }
    }
    float t0 = a0[0] + a0[1];
    float t1 = a1[0] + a1[1];
    float t2 = a2[0] + a2[1];
    float t3 = a3[0] + a3[1];
    // combine the two halves (each summed a disjoint edge subset)
    t0 += __shfl_xor(t0, 32);
    t1 += __shfl_xor(t1, 32);
    t2 += __shfl_xor(t2, 32);
    t3 += __shfl_xor(t3, 32);
    if (!hhi) {
        float4 bv = ((const float4*)b1)[lq];
        float r0 = fmaxf(t0 + bv.x, 0.f);
        float r1 = fmaxf(t1 + bv.y, 0.f);
        float r2 = fmaxf(t2 + bv.z, 0.f);
        float r3 = fmaxf(t3 + bv.w, 0.f);
        bf16x4 o = { (bf16)r0, (bf16)r1, (bf16)r2, (bf16)r3 };
        *(bf16x4*)(h + (size_t)node * NH + lq * 4) = o;
    }
}

// ---------------- gemm2: g = h @ W2 (bf16 out), one thread per row ----------------

__global__ __launch_bounds__(256) void k_gemm2(const bf16* __restrict__ h,
                                               const float* __restrict__ W2,
                                               bf16* __restrict__ g) {
    __shared__ float sW[NH * NC];
    int t = threadIdx.x;
    for (int i = t; i < NH * NC; i += 256) sW[i] = W2[i];
    __syncthreads();
    int row = blockIdx.x * 256 + t;
    if (row >= NN) return;
    const bf16* hr = h + (size_t)row * NH;
    float acc[NC] = {};
    for (int kc = 0; kc < NH / 8; kc++) {
        bf16x8 hv = *(const bf16x8*)(hr + kc * 8);
#pragma unroll
        for (int j = 0; j < 8; j++) {
            float hx = (float)hv[j];
            const float* wr = &sW[(kc * 8 + j) * NC];
#pragma unroll
            for (int c = 0; c < NC; c++) acc[c] += hx * wr[c];
        }
    }
    bf16x8 o0 = { (bf16)acc[0], (bf16)acc[1], (bf16)acc[2],  (bf16)acc[3],
                  (bf16)acc[4], (bf16)acc[5], (bf16)acc[6],  (bf16)acc[7] };
    bf16x8 o1 = { (bf16)acc[8], (bf16)acc[9], (bf16)acc[10], (bf16)acc[11],
                  (bf16)acc[12], (bf16)acc[13], (bf16)acc[14], (bf16)acc[15] };
    bf16* gr = g + (size_t)row * NC;
    *(bf16x8*)gr = o0;
    *(bf16x8*)(gr + 8) = o1;
}

// ---------------- spmm2 + bias + log_softmax fused ----------------
// one wave per node: lane = sub*16 + c; 4 subgroups x 4-deep predicated ILP
// -> 16 edges in flight. Each subgroup vector-loads its own record (16-lane
// same-address broadcast, no SGPR-array selection -> no VGPR spill).

__global__ __launch_bounds__(256) void k_spmm2(const int* __restrict__ row_off,
                                               const int2* __restrict__ edges,
                                               const bf16* __restrict__ g,
                                               const float* __restrict__ b2,
                                               float* __restrict__ out) {
    int node = (blockIdx.x * 256 + threadIdx.x) >> 6;  // 4 nodes per block
    int lane = threadIdx.x & 63;
    int c = lane & 15, sub = lane >> 4;
    int s = row_off[node], e = row_off[node + 1];
    const unsigned short* gbp = (const unsigned short*)g;

    float acc[4] = { 0.f, 0.f, 0.f, 0.f };
    for (int i = s + sub; i < e; i += 16) {
        unsigned sx[4]; float w[4];
#pragma unroll
        for (int k = 0; k < 4; k++) {
            int idx = i + 4 * k;                 // <= e+11: pad covers
            int2 r = edges[idx];
            bool v = idx < e;
            sx[k] = v ? (unsigned)r.x : 0u;
            w[k]  = v ? __int_as_float(r.y) : 0.f;
        }
#pragma unroll
        for (int k = 0; k < 4; k++) {
            unsigned hv = gbp[sx[k] * NC + c];
            acc[k] += w[k] * __int_as_float(hv << 16);
        }
    }
    float a = (acc[0] + acc[1]) + (acc[2] + acc[3]);
    a += __shfl_xor(a, 16);
    a += __shfl_xor(a, 32);
    a += b2[c];
    float m = a;
#pragma unroll
    for (int off = 1; off < 16; off <<= 1) m = fmaxf(m, __shfl_xor(m, off));
    float ex = __expf(a - m);
    float sum = ex;
#pragma unroll
    for (int off = 1; off < 16; off <<= 1) sum += __shfl_xor(sum, off);
    float r = a - m - __logf(sum);
    if (sub == 0) out[(size_t)node * NC + c] = r;
}

// ---------------- launch ----------------

extern "C" void kernel_launch(void* const* d_in, const int* in_sizes, int n_in,
                              void* d_out, int out_size, void* d_ws, size_t ws_size,
                              hipStream_t stream) {
    const float* x  = (const float*)d_in[0];
    const float* W1 = (const float*)d_in[1];
    const float* b1 = (const float*)d_in[2];
    const float* W2 = (const float*)d_in[3];
    const float* b2 = (const float*)d_in[4];
    const float* ew = (const float*)d_in[5];
    const int* src  = (const int*)d_in[6];
    const int* dst  = (const int*)d_in[7];
    float* out = (float*)d_out;

    char* ws = (char*)d_ws;
    unsigned char* h0q = (unsigned char*)(ws + 0);  // NN*NH = 12,800,000 (fp8)
    bf16*  h       = (bf16*)(ws + 25600000);       // 25,600,000
    bf16*  g       = (bf16*)(ws + 51200000);       // NN*NC*2 = 3,200,000
    int*   row_off = (int*)(ws + 54400000);        // (NN+1)*4 = 400,004
    int*   bucket_cursor = (int*)(ws + 54800016);  // 1,564
    int*   bucket_base   = (int*)(ws + 54801584);  // 1,568
    int2*  edges   = (int2*)(ws + 54803168);       // EE*8 + 256 pad = 25,600,256
    bf16*  W1T     = (bf16*)(ws + 80403456);       // 65,536 -> end 80,468,992
    // staged aliases h0q + low part of h: dead before k_gemm1 writes h0q
    int2*  staged  = (int2*)(ws + 0);              // NBKT*BCAP*8 = 30,028,800

    // CSR build
    k_init<<<1, 512, 0, stream>>>(bucket_cursor, edges);
    k_bucket<<<(EE + CHUNK - 1) / CHUNK, 512, 0, stream>>>(src, dst, ew, bucket_cursor, staged);
    k_bscan<<<1, 512, 0, stream>>>(bucket_cursor, bucket_base, row_off);
    k_sort<<<NBKT, 512, 0, stream>>>(staged, bucket_cursor, bucket_base, row_off, edges);

    // layer 1
    k_cvtW1<<<(NF * NH) / 256, 256, 0, stream>>>(W1, W1T);
    k_gemm1<<<(NN + 127) / 128, 512, 0, stream>>>(x, W1T, h0q);
    k_spmm1<<<NN / 4, 256, 0, stream>>>(row_off, edges, h0q, b1, h);

    // layer 2
    k_gemm2<<<(NN + 255) / 256, 256, 0, stream>>>(h, W2, g);
    k_spmm2<<<NN / 4, 256, 0, stream>>>(row_off, edges, g, b2, out);
}

// Round 5
// 397.608 us; speedup vs baseline: 1.0267x; 1.0267x over previous
//
#include <hip/hip_runtime.h>

#define NN 100000
#define EE 3200000
#define NF 256
#define NH 128
#define NC 16
#define NBKT 391       // buckets of 256 dst nodes: ceil(100000/256)
#define BSZ 256        // nodes per bucket
#define BCAP 9600      // staging capacity per bucket (mean 8192, +15.5 sigma)
#define CHUNK 4096     // edges per k_bucket block

typedef __bf16 bf16;
typedef bf16 bf16x2 __attribute__((ext_vector_type(2)));
typedef bf16 bf16x4 __attribute__((ext_vector_type(4)));
typedef bf16 bf16x8 __attribute__((ext_vector_type(8)));
typedef float f32x2 __attribute__((ext_vector_type(2)));
typedef float f32x4 __attribute__((ext_vector_type(4)));

// ---------------- CSR build: bucket partition + per-bucket LDS sort ----------------

__global__ void k_init(int* __restrict__ bucket_cursor, int2* __restrict__ edges) {
    int t = threadIdx.x;
    if (t < NBKT) bucket_cursor[t] = t * BCAP;
    if (t >= 480) edges[EE + t - 480] = make_int2(0, 0);  // 32-record pad for spmm overrun
}

// Pass 1: partition edges into NBKT staging regions, LDS-binned so global
// writes are contiguous runs per bucket instead of 8B scatter.
__global__ __launch_bounds__(512) void k_bucket(const int* __restrict__ src,
                                                const int* __restrict__ dst,
                                                const float* __restrict__ ew,
                                                int* __restrict__ bucket_cursor,
                                                int2* __restrict__ staged) {
    __shared__ int2 recs[CHUNK];              // 32 KB
    __shared__ unsigned short bkt[CHUNK];     // 8 KB
    __shared__ int cnt[NBKT], start[NBKT + 1], cur[NBKT], gbase[NBKT];
    __shared__ int sc[512];
    int t = threadIdx.x;
    int base = blockIdx.x * CHUNK;
    int n = EE - base; if (n > CHUNK) n = CHUNK;
    if (t < NBKT) cnt[t] = 0;
    __syncthreads();
    for (int i = t; i < n; i += 512) {
        atomicAdd(&cnt[dst[base + i] >> 8], 1);
    }
    __syncthreads();
    sc[t] = (t < NBKT) ? cnt[t] : 0;
    __syncthreads();
    for (int off = 1; off < 512; off <<= 1) {
        int v = (t >= off) ? sc[t - off] : 0;
        __syncthreads();
        sc[t] += v;
        __syncthreads();
    }
    if (t < NBKT) { start[t] = sc[t] - cnt[t]; cur[t] = sc[t] - cnt[t]; }
    if (t == 0) start[NBKT] = sc[511];
    __syncthreads();
    for (int i = t; i < n; i += 512) {
        int d = dst[base + i];
        int b = d >> 8;
        int p = atomicAdd(&cur[b], 1);
        recs[p] = make_int2(src[base + i] | ((d & 255) << 17), __float_as_int(ew[base + i]));
        bkt[p] = (unsigned short)b;
    }
    __syncthreads();
    if (t < NBKT) gbase[t] = atomicAdd(&bucket_cursor[t], start[t + 1] - start[t]);
    __syncthreads();
    for (int i = t; i < n; i += 512) {
        int b = bkt[i];
        staged[gbase[b] + (i - start[b])] = recs[i];
    }
}

// Exclusive scan of per-bucket counts -> global base of each bucket in edges[].
__global__ void k_bscan(const int* __restrict__ bucket_cursor,
                        int* __restrict__ bucket_base, int* __restrict__ row_off) {
    __shared__ int s[512];
    int t = threadIdx.x;
    int v = (t < NBKT) ? (bucket_cursor[t] - t * BCAP) : 0;
    s[t] = v;
    __syncthreads();
    for (int off = 1; off < 512; off <<= 1) {
        int x = (t >= off) ? s[t - off] : 0;
        __syncthreads();
        s[t] += x;
        __syncthreads();
    }
    if (t < NBKT) bucket_base[t] = s[t] - v;
    if (t == 0) { bucket_base[NBKT] = EE; row_off[NN] = EE; }
}

// One block per bucket: LDS counting sort. 512 threads, 79.9 KB LDS ->
// 2 blocks/CU (16 waves), 391 blocks ~ one balanced round over 256 CUs.
__global__ __launch_bounds__(512) void k_sort(const int2* __restrict__ staged,
                                              const int* __restrict__ bucket_cursor,
                                              const int* __restrict__ bucket_base,
                                              int* __restrict__ row_off,
                                              int2* __restrict__ edges) {
    __shared__ int2 lrec[BCAP];               // 76.8 KB
    __shared__ int lcnt[BSZ], lstart[BSZ], lcur[BSZ];
    int t = threadIdx.x;
    int b = blockIdx.x;
    int n = bucket_cursor[b] - b * BCAP;
    int gb = bucket_base[b];
    const int2* sp = staged + (size_t)b * BCAP;
    if (t < BSZ) lcnt[t] = 0;
    __syncthreads();
    for (int i = t; i < n; i += 512) {
        int2 r = sp[i];
        lrec[i] = r;
        atomicAdd(&lcnt[r.x >> 17], 1);
    }
    __syncthreads();
    if (t < BSZ) lstart[t] = lcnt[t];
    __syncthreads();
    for (int off = 1; off < BSZ; off <<= 1) {
        int v = 0;
        if (t < BSZ && t >= off) v = lstart[t - off];
        __syncthreads();
        if (t < BSZ) lstart[t] += v;
        __syncthreads();
    }
    if (t < BSZ) {
        int ex = lstart[t] - lcnt[t];        // exclusive within-bucket start
        lcur[t] = ex;
        int node = (b << 8) + t;
        if (node < NN) row_off[node] = gb + ex;
    }
    __syncthreads();
    for (int i = t; i < n; i += 512) {
        int2 r = lrec[i];
        int d = r.x >> 17;
        int p = atomicAdd(&lcur[d], 1);
        edges[gb + p] = make_int2(r.x & 0x1FFFF, r.y);
    }
}

// ---------------- layer 1: x @ W1 (bf16 MFMA), h0 stored as FP8 e4m3 ----------------

__global__ void k_cvtW1(const float* __restrict__ W1, bf16* __restrict__ W1T) {
    int i = blockIdx.x * 256 + threadIdx.x;  // 32768 elems, W1 is [NF][NH]
    int k = i >> 7, n = i & 127;
    W1T[n * NF + k] = (bf16)W1[i];           // W1T: [NH][NF]
}

// v4: staging via global_load_lds width=16 (async DMA, no VGPR roundtrip).
// LDS dest must be linear (wave-uniform base + lane*16), so the XOR swizzle
// is applied to the per-lane global SOURCE address instead (same involution;
// reads unchanged). Swapped MFMA operands: D = W x^T so each lane's 4 acc
// regs are 4 consecutive features of its own x-row -> 1 dword fp8 store per
// ct (8 stores total). 512 threads, 1 tile/wave -> 16 waves/CU at 64 KB LDS.
__global__ __launch_bounds__(512, 4) void k_gemm1(const float* __restrict__ x,
                                                  const bf16* __restrict__ W1T,
                                                  unsigned char* __restrict__ h0q) {
    __shared__ unsigned short sW[NH * NF];   // 64 KB
    int t = threadIdx.x;
    int lane = t & 63;
    int wid = t >> 6;      // 0..7
    int m = lane & 15;     // x row within 16-tile
    int kg = lane >> 4;    // k-group 0..3
    int row = blockIdx.x * 128 + wid * 16 + m;
    bool in = (row < NN);
    const float* xr = x + (size_t)row * NF;

    // stage W1T -> LDS first (async issue-only, fetches overlap the x loads).
    // dest chunk cid=(n,ch) linear; source chunk = ch ^ (n&7) of row n.
#pragma unroll
    for (int it = 0; it < 8; it++) {
        int cid = t + it * 512;                        // 4096 chunks of 16 B
        int n = cid >> 5, ch = cid & 31;
        const bf16* srcp = W1T + (size_t)n * NF + ((ch ^ (n & 7)) << 3);
        __builtin_amdgcn_global_load_lds(
            (const __attribute__((address_space(1))) void*)srcp,
            (__attribute__((address_space(3))) void*)&sW[cid << 3],
            16, 0, 0);
    }

    // x loads: 16 dwordx4 in flight under the staging DMA
    bf16x8 a[8];
#pragma unroll
    for (int kt = 0; kt < 8; kt++) {
        int k0 = kt * 32 + kg * 8;
        float4 u = in ? *(const float4*)(xr + k0)     : make_float4(0.f, 0.f, 0.f, 0.f);
        float4 v = in ? *(const float4*)(xr + k0 + 4) : make_float4(0.f, 0.f, 0.f, 0.f);
        bf16x8 av = { (bf16)u.x, (bf16)u.y, (bf16)u.z, (bf16)u.w,
                      (bf16)v.x, (bf16)v.y, (bf16)v.z, (bf16)v.w };
        a[kt] = av;
    }
    __syncthreads();   // drains vmcnt(0): staging + x loads

    f32x4 acc[8] = {};
#pragma unroll
    for (int ct = 0; ct < 8; ct++) {
        int brow = ct * 16 + m;                  // W feature row (A operand)
        const unsigned short* bp = sW + brow * NF;
        int sw = brow & 7;
#pragma unroll
        for (int kt = 0; kt < 8; kt++) {
            int ch = kt * 4 + kg;
            bf16x8 b = *(const bf16x8*)(bp + ((ch ^ sw) << 3));
            // A = W fragment, B = x fragment: D[feat][xrow]
            acc[ct] = __builtin_amdgcn_mfma_f32_16x16x32_bf16(b, a[kt], acc[ct], 0, 0, 0);
        }
    }

    // D layout: col = lane&15 = this lane's own x row, reg = feature
    // -> 4 consecutive features -> 1 dword fp8 store per ct.
    if (in) {
        unsigned char* rp = h0q + (size_t)row * NH + kg * 4;
#pragma unroll
        for (int ct = 0; ct < 8; ct++) {
            unsigned lo = (unsigned)__builtin_amdgcn_cvt_pk_fp8_f32(
                              acc[ct][0], acc[ct][1], 0, false);
            unsigned pk = (unsigned)__builtin_amdgcn_cvt_pk_fp8_f32(
                              acc[ct][2], acc[ct][3], lo, true);
            *(unsigned*)(rp + ct * 16) = pk;
        }
    }
}

// ---------------- spmm1: h = relu(A @ h0 + b1) ----------------
// v3 (reverted from v4's 32-edge unroll, which cost +30% VALU and +20%
// padded-edge waste at mean degree 32): half-wave edge pairing, 16 edges
// per iter, 8 dword gathers in flight. Lanes 0-31 take even edges, 32-63
// odd; each lane gathers a dword = 4 fp8 channels, so one gather serves 2
// edges and address math runs once per pair. Edge records on the scalar
// pipe; OOB -> src=0,w=0 via s_cselect.

__global__ __launch_bounds__(256) void k_spmm1(const int* __restrict__ row_off,
                                               const int2* __restrict__ edges,
                                               const unsigned char* __restrict__ h0q,
                                               const float* __restrict__ b1,
                                               bf16* __restrict__ h) {
    int wid = __builtin_amdgcn_readfirstlane(threadIdx.x >> 6);
    int node = blockIdx.x * 4 + wid;               // wave-uniform, always < NN
    int lane = threadIdx.x & 63;
    int lq = lane & 31;
    bool hhi = lane >= 32;                         // loop-invariant half mask
    int s = row_off[node], e = row_off[node + 1];  // uniform -> s_load

    unsigned loff = (unsigned)lq * 4u;             // byte offset within row

    float a0[2] = {0.f, 0.f}, a1[2] = {0.f, 0.f};
    float a2[2] = {0.f, 0.f}, a3[2] = {0.f, 0.f};

    for (int i = s; i < e; i += 16) {
        int2 q[16];
#pragma unroll
        for (int j = 0; j < 16; j++) q[j] = edges[i + j];   // uniform -> s_load
        unsigned so[8]; float wo[8];
#pragma unroll
        for (int j = 0; j < 8; j++) {
            bool v0 = (i + 2 * j)     < e;                   // scalar cmp
            bool v1 = (i + 2 * j + 1) < e;
            unsigned s0 = v0 ? (unsigned)q[2 * j].x : 0u;    // s_cselect
            unsigned s1 = v1 ? (unsigned)q[2 * j + 1].x : 0u;
            float w0 = v0 ? __int_as_float(q[2 * j].y) : 0.f;
            float w1 = v1 ? __int_as_float(q[2 * j + 1].y) : 0.f;
            so[j] = hhi ? s1 : s0;                           // v_cndmask
            wo[j] = hhi ? w1 : w0;                           // v_cndmask
        }
        unsigned dv[8];
#pragma unroll
        for (int j = 0; j < 8; j++) {
            unsigned off = (so[j] << 7) + loff;              // 1 VALU, 24-bit range
            dv[j] = *(const unsigned*)(h0q + off);           // 8 gathers in flight
        }
#pragma unroll
        for (int j = 0; j < 8; j++) {
            f32x2 f01 = __builtin_amdgcn_cvt_pk_f32_fp8(dv[j], false);
            f32x2 f23 = __builtin_amdgcn_cvt_pk_f32_fp8(dv[j], true);
            int p = j & 1;
            a0[p] += wo[j] * f01[0];
            a1[p] += wo[j] * f01[1];
            a2[p] += wo[j] * f23[0];
            a3[p] += wo[j] * f23[1];
        }
    }
    float t0 = a0[0] + a0[1];
    float t1 = a1[0] + a1[1];
    float t2 = a2[0] + a2[1];
    float t3 = a3[0] + a3[1];
    // combine the two halves (each summed a disjoint edge subset)
    t0 += __shfl_xor(t0, 32);
    t1 += __shfl_xor(t1, 32);
    t2 += __shfl_xor(t2, 32);
    t3 += __shfl_xor(t3, 32);
    if (!hhi) {
        float4 bv = ((const float4*)b1)[lq];
        float r0 = fmaxf(t0 + bv.x, 0.f);
        float r1 = fmaxf(t1 + bv.y, 0.f);
        float r2 = fmaxf(t2 + bv.z, 0.f);
        float r3 = fmaxf(t3 + bv.w, 0.f);
        bf16x4 o = { (bf16)r0, (bf16)r1, (bf16)r2, (bf16)r3 };
        *(bf16x4*)(h + (size_t)node * NH + lq * 4) = o;
    }
}

// ---------------- gemm2: g = h @ W2 (bf16 out), one thread per row ----------------

__global__ __launch_bounds__(256) void k_gemm2(const bf16* __restrict__ h,
                                               const float* __restrict__ W2,
                                               bf16* __restrict__ g) {
    __shared__ float sW[NH * NC];
    int t = threadIdx.x;
    for (int i = t; i < NH * NC; i += 256) sW[i] = W2[i];
    __syncthreads();
    int row = blockIdx.x * 256 + t;
    if (row >= NN) return;
    const bf16* hr = h + (size_t)row * NH;
    float acc[NC] = {};
    for (int kc = 0; kc < NH / 8; kc++) {
        bf16x8 hv = *(const bf16x8*)(hr + kc * 8);
#pragma unroll
        for (int j = 0; j < 8; j++) {
            float hx = (float)hv[j];
            const float* wr = &sW[(kc * 8 + j) * NC];
#pragma unroll
            for (int c = 0; c < NC; c++) acc[c] += hx * wr[c];
        }
    }
    bf16x8 o0 = { (bf16)acc[0], (bf16)acc[1], (bf16)acc[2],  (bf16)acc[3],
                  (bf16)acc[4], (bf16)acc[5], (bf16)acc[6],  (bf16)acc[7] };
    bf16x8 o1 = { (bf16)acc[8], (bf16)acc[9], (bf16)acc[10], (bf16)acc[11],
                  (bf16)acc[12], (bf16)acc[13], (bf16)acc[14], (bf16)acc[15] };
    bf16* gr = g + (size_t)row * NC;
    *(bf16x8*)gr = o0;
    *(bf16x8*)(gr + 8) = o1;
}

// ---------------- spmm2 + bias + log_softmax fused ----------------
// one wave per node: lane = sub*16 + c; 4 subgroups x 4-deep predicated ILP
// -> 16 edges in flight. Each subgroup vector-loads its own record (16-lane
// same-address broadcast, no SGPR-array selection -> no VGPR spill).

__global__ __launch_bounds__(256) void k_spmm2(const int* __restrict__ row_off,
                                               const int2* __restrict__ edges,
                                               const bf16* __restrict__ g,
                                               const float* __restrict__ b2,
                                               float* __restrict__ out) {
    int node = (blockIdx.x * 256 + threadIdx.x) >> 6;  // 4 nodes per block
    int lane = threadIdx.x & 63;
    int c = lane & 15, sub = lane >> 4;
    int s = row_off[node], e = row_off[node + 1];
    const unsigned short* gbp = (const unsigned short*)g;

    float acc[4] = { 0.f, 0.f, 0.f, 0.f };
    for (int i = s + sub; i < e; i += 16) {
        unsigned sx[4]; float w[4];
#pragma unroll
        for (int k = 0; k < 4; k++) {
            int idx = i + 4 * k;                 // <= e+11: pad covers
            int2 r = edges[idx];
            bool v = idx < e;
            sx[k] = v ? (unsigned)r.x : 0u;
            w[k]  = v ? __int_as_float(r.y) : 0.f;
        }
#pragma unroll
        for (int k = 0; k < 4; k++) {
            unsigned hv = gbp[sx[k] * NC + c];
            acc[k] += w[k] * __int_as_float(hv << 16);
        }
    }
    float a = (acc[0] + acc[1]) + (acc[2] + acc[3]);
    a += __shfl_xor(a, 16);
    a += __shfl_xor(a, 32);
    a += b2[c];
    float m = a;
#pragma unroll
    for (int off = 1; off < 16; off <<= 1) m = fmaxf(m, __shfl_xor(m, off));
    float ex = __expf(a - m);
    float sum = ex;
#pragma unroll
    for (int off = 1; off < 16; off <<= 1) sum += __shfl_xor(sum, off);
    float r = a - m - __logf(sum);
    if (sub == 0) out[(size_t)node * NC + c] = r;
}

// ---------------- launch ----------------

extern "C" void kernel_launch(void* const* d_in, const int* in_sizes, int n_in,
                              void* d_out, int out_size, void* d_ws, size_t ws_size,
                              hipStream_t stream) {
    const float* x  = (const float*)d_in[0];
    const float* W1 = (const float*)d_in[1];
    const float* b1 = (const float*)d_in[2];
    const float* W2 = (const float*)d_in[3];
    const float* b2 = (const float*)d_in[4];
    const float* ew = (const float*)d_in[5];
    const int* src  = (const int*)d_in[6];
    const int* dst  = (const int*)d_in[7];
    float* out = (float*)d_out;

    char* ws = (char*)d_ws;
    unsigned char* h0q = (unsigned char*)(ws + 0);  // NN*NH = 12,800,000 (fp8)
    bf16*  h       = (bf16*)(ws + 25600000);       // 25,600,000
    bf16*  g       = (bf16*)(ws + 51200000);       // NN*NC*2 = 3,200,000
    int*   row_off = (int*)(ws + 54400000);        // (NN+1)*4 = 400,004
    int*   bucket_cursor = (int*)(ws + 54800016);  // 1,564
    int*   bucket_base   = (int*)(ws + 54801584);  // 1,568
    int2*  edges   = (int2*)(ws + 54803168);       // EE*8 + 256 pad = 25,600,256
    bf16*  W1T     = (bf16*)(ws + 80403456);       // 65,536 -> end 80,468,992
    // staged aliases h0q + low part of h: dead before k_gemm1 writes h0q
    int2*  staged  = (int2*)(ws + 0);              // NBKT*BCAP*8 = 30,028,800

    // CSR build
    k_init<<<1, 512, 0, stream>>>(bucket_cursor, edges);
    k_bucket<<<(EE + CHUNK - 1) / CHUNK, 512, 0, stream>>>(src, dst, ew, bucket_cursor, staged);
    k_bscan<<<1, 512, 0, stream>>>(bucket_cursor, bucket_base, row_off);
    k_sort<<<NBKT, 512, 0, stream>>>(staged, bucket_cursor, bucket_base, row_off, edges);

    // layer 1
    k_cvtW1<<<(NF * NH) / 256, 256, 0, stream>>>(W1, W1T);
    k_gemm1<<<(NN + 127) / 128, 512, 0, stream>>>(x, W1T, h0q);
    k_spmm1<<<NN / 4, 256, 0, stream>>>(row_off, edges, h0q, b1, h);

    // layer 2
    k_gemm2<<<(NN + 255) / 256, 256, 0, stream>>>(h, W2, g);
    k_spmm2<<<NN / 4, 256, 0, stream>>>(row_off, edges, g, b2, out);
}

// Round 6
// 384.371 us; speedup vs baseline: 1.0621x; 1.0344x over previous
//
#include <hip/hip_runtime.h>

#define NN 100000
#define EE 3200000
#define NF 256
#define NH 128
#define NC 16
#define NBKT 391       // buckets of 256 dst nodes: ceil(100000/256)
#define BSZ 256        // nodes per bucket
#define BCAP 9600      // staging capacity per bucket (mean 8192, +15.5 sigma)
#define CHUNK 4096     // edges per k_bucket block

typedef __bf16 bf16;
typedef bf16 bf16x2 __attribute__((ext_vector_type(2)));
typedef bf16 bf16x4 __attribute__((ext_vector_type(4)));
typedef bf16 bf16x8 __attribute__((ext_vector_type(8)));
typedef float f32x2 __attribute__((ext_vector_type(2)));
typedef float f32x4 __attribute__((ext_vector_type(4)));

// ---------------- CSR build: bucket partition + per-bucket LDS sort ----------------

__global__ void k_init(int* __restrict__ bucket_cursor, int2* __restrict__ edges) {
    int t = threadIdx.x;
    if (t < NBKT) bucket_cursor[t] = t * BCAP;
    if (t >= 480) edges[EE + t - 480] = make_int2(0, 0);  // 32-record pad for spmm overrun
}

// Pass 1: partition edges into NBKT staging regions, LDS-binned so global
// writes are contiguous runs per bucket instead of 8B scatter.
__global__ __launch_bounds__(512) void k_bucket(const int* __restrict__ src,
                                                const int* __restrict__ dst,
                                                const float* __restrict__ ew,
                                                int* __restrict__ bucket_cursor,
                                                int2* __restrict__ staged) {
    __shared__ int2 recs[CHUNK];              // 32 KB
    __shared__ unsigned short bkt[CHUNK];     // 8 KB
    __shared__ int cnt[NBKT], start[NBKT + 1], cur[NBKT], gbase[NBKT];
    __shared__ int sc[512];
    int t = threadIdx.x;
    int base = blockIdx.x * CHUNK;
    int n = EE - base; if (n > CHUNK) n = CHUNK;
    if (t < NBKT) cnt[t] = 0;
    __syncthreads();
    for (int i = t; i < n; i += 512) {
        atomicAdd(&cnt[dst[base + i] >> 8], 1);
    }
    __syncthreads();
    sc[t] = (t < NBKT) ? cnt[t] : 0;
    __syncthreads();
    for (int off = 1; off < 512; off <<= 1) {
        int v = (t >= off) ? sc[t - off] : 0;
        __syncthreads();
        sc[t] += v;
        __syncthreads();
    }
    if (t < NBKT) { start[t] = sc[t] - cnt[t]; cur[t] = sc[t] - cnt[t]; }
    if (t == 0) start[NBKT] = sc[511];
    __syncthreads();
    for (int i = t; i < n; i += 512) {
        int d = dst[base + i];
        int b = d >> 8;
        int p = atomicAdd(&cur[b], 1);
        recs[p] = make_int2(src[base + i] | ((d & 255) << 17), __float_as_int(ew[base + i]));
        bkt[p] = (unsigned short)b;
    }
    __syncthreads();
    if (t < NBKT) gbase[t] = atomicAdd(&bucket_cursor[t], start[t + 1] - start[t]);
    __syncthreads();
    for (int i = t; i < n; i += 512) {
        int b = bkt[i];
        staged[gbase[b] + (i - start[b])] = recs[i];
    }
}

// Exclusive scan of per-bucket counts -> global base of each bucket in edges[].
__global__ void k_bscan(const int* __restrict__ bucket_cursor,
                        int* __restrict__ bucket_base, int* __restrict__ row_off) {
    __shared__ int s[512];
    int t = threadIdx.x;
    int v = (t < NBKT) ? (bucket_cursor[t] - t * BCAP) : 0;
    s[t] = v;
    __syncthreads();
    for (int off = 1; off < 512; off <<= 1) {
        int x = (t >= off) ? s[t - off] : 0;
        __syncthreads();
        s[t] += x;
        __syncthreads();
    }
    if (t < NBKT) bucket_base[t] = s[t] - v;
    if (t == 0) { bucket_base[NBKT] = EE; row_off[NN] = EE; }
}

__global__ void k_cvtW1(const float* __restrict__ W1, bf16* __restrict__ W1T) {
    int i = blockIdx.x * 256 + threadIdx.x;  // 32768 elems, W1 is [NF][NH]
    int k = i >> 7, n = i & 127;
    W1T[n * NF + k] = (bf16)W1[i];           // W1T: [NH][NF]
}

// ---------------- fused: k_sort (391 blocks) || k_gemm1 (782 blocks) ----------------
// sort and gemm1 are independent (sort needs bucket+bscan; gemm1 needs cvtW1);
// on one stream they serialize, so fuse into one kernel with disjoint block
// ranges -> cost ~ max instead of sum. LDS union = max(79.9, 64) KB keeps both
// at their native 2 blocks/CU. bid%3==0 -> sort, else gemm1 (interleave spreads
// the memory-bound and compute-bound blocks across XCDs). REQUIRES staged to
// NOT alias h0q (gemm1 writes h0q while sort reads staged).

union SortGemmSmem {
    struct {
        int2 lrec[BCAP];                      // 76.8 KB
        int lcnt[BSZ], lstart[BSZ], lcur[BSZ];
    } s;
    unsigned short sW[NH * NF];               // 64 KB
};

__device__ __forceinline__ void sort_body(SortGemmSmem& u, int b,
                                          const int2* __restrict__ staged,
                                          const int* __restrict__ bucket_cursor,
                                          const int* __restrict__ bucket_base,
                                          int* __restrict__ row_off,
                                          int2* __restrict__ edges) {
    int t = threadIdx.x;
    int n = bucket_cursor[b] - b * BCAP;
    int gb = bucket_base[b];
    const int2* sp = staged + (size_t)b * BCAP;
    if (t < BSZ) u.s.lcnt[t] = 0;
    __syncthreads();
    for (int i = t; i < n; i += 512) {
        int2 r = sp[i];
        u.s.lrec[i] = r;
        atomicAdd(&u.s.lcnt[r.x >> 17], 1);
    }
    __syncthreads();
    if (t < BSZ) u.s.lstart[t] = u.s.lcnt[t];
    __syncthreads();
    for (int off = 1; off < BSZ; off <<= 1) {
        int v = 0;
        if (t < BSZ && t >= off) v = u.s.lstart[t - off];
        __syncthreads();
        if (t < BSZ) u.s.lstart[t] += v;
        __syncthreads();
    }
    if (t < BSZ) {
        int ex = u.s.lstart[t] - u.s.lcnt[t];   // exclusive within-bucket start
        u.s.lcur[t] = ex;
        int node = (b << 8) + t;
        if (node < NN) row_off[node] = gb + ex;
    }
    __syncthreads();
    for (int i = t; i < n; i += 512) {
        int2 r = u.s.lrec[i];
        int d = r.x >> 17;
        int p = atomicAdd(&u.s.lcur[d], 1);
        edges[gb + p] = make_int2(r.x & 0x1FFFF, r.y);
    }
}

__device__ __forceinline__ void gemm1_body(SortGemmSmem& u, int gid,
                                           const float* __restrict__ x,
                                           const bf16* __restrict__ W1T,
                                           unsigned char* __restrict__ h0q) {
    int t = threadIdx.x;
    int lane = t & 63;
    int wid = t >> 6;      // 0..7
    int m = lane & 15;     // x row within 16-tile
    int kg = lane >> 4;    // k-group 0..3
    int row = gid * 128 + wid * 16 + m;
    bool in = (row < NN);
    const float* xr = x + (size_t)row * NF;

    // stage W1T -> LDS via async DMA; dest linear, XOR swizzle on the SOURCE.
#pragma unroll
    for (int it = 0; it < 8; it++) {
        int cid = t + it * 512;                        // 4096 chunks of 16 B
        int n = cid >> 5, ch = cid & 31;
        const bf16* srcp = W1T + (size_t)n * NF + ((ch ^ (n & 7)) << 3);
        __builtin_amdgcn_global_load_lds(
            (const __attribute__((address_space(1))) void*)srcp,
            (__attribute__((address_space(3))) void*)&u.sW[cid << 3],
            16, 0, 0);
    }

    // x loads: 16 dwordx4 in flight under the staging DMA
    bf16x8 a[8];
#pragma unroll
    for (int kt = 0; kt < 8; kt++) {
        int k0 = kt * 32 + kg * 8;
        float4 uu = in ? *(const float4*)(xr + k0)     : make_float4(0.f, 0.f, 0.f, 0.f);
        float4 vv = in ? *(const float4*)(xr + k0 + 4) : make_float4(0.f, 0.f, 0.f, 0.f);
        bf16x8 av = { (bf16)uu.x, (bf16)uu.y, (bf16)uu.z, (bf16)uu.w,
                      (bf16)vv.x, (bf16)vv.y, (bf16)vv.z, (bf16)vv.w };
        a[kt] = av;
    }
    __syncthreads();   // drains vmcnt(0): staging + x loads

    f32x4 acc[8] = {};
#pragma unroll
    for (int ct = 0; ct < 8; ct++) {
        int brow = ct * 16 + m;                  // W feature row (A operand)
        const unsigned short* bp = u.sW + brow * NF;
        int sw = brow & 7;
#pragma unroll
        for (int kt = 0; kt < 8; kt++) {
            int ch = kt * 4 + kg;
            bf16x8 b = *(const bf16x8*)(bp + ((ch ^ sw) << 3));
            // A = W fragment, B = x fragment: D[feat][xrow]
            acc[ct] = __builtin_amdgcn_mfma_f32_16x16x32_bf16(b, a[kt], acc[ct], 0, 0, 0);
        }
    }

    // D: col = lane&15 = own x row, reg = feature -> 1 dword fp8 store per ct.
    if (in) {
        unsigned char* rp = h0q + (size_t)row * NH + kg * 4;
#pragma unroll
        for (int ct = 0; ct < 8; ct++) {
            unsigned lo = (unsigned)__builtin_amdgcn_cvt_pk_fp8_f32(
                              acc[ct][0], acc[ct][1], 0, false);
            unsigned pk = (unsigned)__builtin_amdgcn_cvt_pk_fp8_f32(
                              acc[ct][2], acc[ct][3], lo, true);
            *(unsigned*)(rp + ct * 16) = pk;
        }
    }
}

__global__ __launch_bounds__(512, 4) void k_sortgemm1(const int2* __restrict__ staged,
                                                      const int* __restrict__ bucket_cursor,
                                                      const int* __restrict__ bucket_base,
                                                      int* __restrict__ row_off,
                                                      int2* __restrict__ edges,
                                                      const float* __restrict__ x,
                                                      const bf16* __restrict__ W1T,
                                                      unsigned char* __restrict__ h0q) {
    __shared__ SortGemmSmem u;
    int bid = blockIdx.x;
    int r3 = bid % 3;
    if (r3 == 0) sort_body(u, bid / 3, staged, bucket_cursor, bucket_base, row_off, edges);
    else         gemm1_body(u, (bid / 3) * 2 + r3 - 1, x, W1T, h0q);
}

// ---------------- spmm1 + gemm2 fused: g = relu(A @ h0 + b1) @ W2 ----------------
// v5: gemm2 folded into the epilogue. After the shfl combine every lane holds
// the node's h[4lq..4lq+3] (f32, pre-quantization). Lanes 0-31 stage the row
// to LDS (same-wave only, no barrier: per-wave LDS ops are in-order); lane
// (kg,c)=(lane>>4, lane&15) holds W2[kg*32..][c] in 32 VGPRs, does 32 FMA,
// 2 shfl_xor -> g. Eliminates the h buffer (51 MB round-trip) and the
// separate k_gemm2 kernel; epilogue rides idle issue slots of this
// latency-bound gather kernel. Gather loop is the proven v3 structure.

__global__ __launch_bounds__(256) void k_spmm1g(const int* __restrict__ row_off,
                                                const int2* __restrict__ edges,
                                                const unsigned char* __restrict__ h0q,
                                                const float* __restrict__ b1,
                                                const float* __restrict__ W2,
                                                bf16* __restrict__ g) {
    __shared__ float hs[4][NH];                    // 2 KB
    int wid = __builtin_amdgcn_readfirstlane(threadIdx.x >> 6);
    int node = blockIdx.x * 4 + wid;               // wave-uniform, always < NN
    int lane = threadIdx.x & 63;
    int lq = lane & 31;
    bool hhi = lane >= 32;                         // loop-invariant half mask
    int kg = lane >> 4, c = lane & 15;

    // W2 column slice in registers: w2r[j] = W2[kg*32+j][c]
    float w2r[32];
#pragma unroll
    for (int j = 0; j < 32; j++) w2r[j] = W2[(kg * 32 + j) * NC + c];

    int s = row_off[node], e = row_off[node + 1];  // uniform -> s_load
    unsigned loff = (unsigned)lq * 4u;             // byte offset within row

    float a0[2] = {0.f, 0.f}, a1[2] = {0.f, 0.f};
    float a2[2] = {0.f, 0.f}, a3[2] = {0.f, 0.f};

    for (int i = s; i < e; i += 16) {
        int2 q[16];
#pragma unroll
        for (int j = 0; j < 16; j++) q[j] = edges[i + j];   // uniform -> s_load
        unsigned so[8]; float wo[8];
#pragma unroll
        for (int j = 0; j < 8; j++) {
            bool v0 = (i + 2 * j)     < e;                   // scalar cmp
            bool v1 = (i + 2 * j + 1) < e;
            unsigned s0 = v0 ? (unsigned)q[2 * j].x : 0u;    // s_cselect
            unsigned s1 = v1 ? (unsigned)q[2 * j + 1].x : 0u;
            float w0 = v0 ? __int_as_float(q[2 * j].y) : 0.f;
            float w1 = v1 ? __int_as_float(q[2 * j + 1].y) : 0.f;
            so[j] = hhi ? s1 : s0;                           // v_cndmask
            wo[j] = hhi ? w1 : w0;                           // v_cndmask
        }
        unsigned dv[8];
#pragma unroll
        for (int j = 0; j < 8; j++) {
            unsigned off = (so[j] << 7) + loff;              // 1 VALU, 24-bit range
            dv[j] = *(const unsigned*)(h0q + off);           // 8 gathers in flight
        }
#pragma unroll
        for (int j = 0; j < 8; j++) {
            f32x2 f01 = __builtin_amdgcn_cvt_pk_f32_fp8(dv[j], false);
            f32x2 f23 = __builtin_amdgcn_cvt_pk_f32_fp8(dv[j], true);
            int p = j & 1;
            a0[p] += wo[j] * f01[0];
            a1[p] += wo[j] * f01[1];
            a2[p] += wo[j] * f23[0];
            a3[p] += wo[j] * f23[1];
        }
    }
    float t0 = a0[0] + a0[1];
    float t1 = a1[0] + a1[1];
    float t2 = a2[0] + a2[1];
    float t3 = a3[0] + a3[1];
    // combine the two halves (each summed a disjoint edge subset)
    t0 += __shfl_xor(t0, 32);
    t1 += __shfl_xor(t1, 32);
    t2 += __shfl_xor(t2, 32);
    t3 += __shfl_xor(t3, 32);

    // h values (all lanes have them; channels 4lq..4lq+3)
    float4 bv = ((const float4*)b1)[lq];
    float r0 = fmaxf(t0 + bv.x, 0.f);
    float r1 = fmaxf(t1 + bv.y, 0.f);
    float r2 = fmaxf(t2 + bv.z, 0.f);
    float r3 = fmaxf(t3 + bv.w, 0.f);
    if (!hhi) *(float4*)&hs[wid][lq * 4] = make_float4(r0, r1, r2, r3);
    // same-wave write->read: LDS pipe is in-order per wave; compiler keeps
    // program order (may-alias) and inserts lgkmcnt before use.
    const float* hp = &hs[wid][kg * 32];
    float p = 0.f;
#pragma unroll
    for (int j = 0; j < 32; j++) p += hp[j] * w2r[j];
    p += __shfl_xor(p, 16);                        // combine kg pairs
    p += __shfl_xor(p, 32);
    if (lane < 16) g[(size_t)node * NC + lane] = (bf16)p;
}

// ---------------- spmm2 + bias + log_softmax fused ----------------
// one wave per node: lane = sub*16 + c; 4 subgroups x 4-deep predicated ILP
// -> 16 edges in flight. Each subgroup vector-loads its own record (16-lane
// same-address broadcast, no SGPR-array selection -> no VGPR spill).

__global__ __launch_bounds__(256) void k_spmm2(const int* __restrict__ row_off,
                                               const int2* __restrict__ edges,
                                               const bf16* __restrict__ g,
                                               const float* __restrict__ b2,
                                               float* __restrict__ out) {
    int node = (blockIdx.x * 256 + threadIdx.x) >> 6;  // 4 nodes per block
    int lane = threadIdx.x & 63;
    int c = lane & 15, sub = lane >> 4;
    int s = row_off[node], e = row_off[node + 1];
    const unsigned short* gbp = (const unsigned short*)g;

    float acc[4] = { 0.f, 0.f, 0.f, 0.f };
    for (int i = s + sub; i < e; i += 16) {
        unsigned sx[4]; float w[4];
#pragma unroll
        for (int k = 0; k < 4; k++) {
            int idx = i + 4 * k;                 // <= e+11: pad covers
            int2 r = edges[idx];
            bool v = idx < e;
            sx[k] = v ? (unsigned)r.x : 0u;
            w[k]  = v ? __int_as_float(r.y) : 0.f;
        }
#pragma unroll
        for (int k = 0; k < 4; k++) {
            unsigned hv = gbp[sx[k] * NC + c];
            acc[k] += w[k] * __int_as_float(hv << 16);
        }
    }
    float a = (acc[0] + acc[1]) + (acc[2] + acc[3]);
    a += __shfl_xor(a, 16);
    a += __shfl_xor(a, 32);
    a += b2[c];
    float m = a;
#pragma unroll
    for (int off = 1; off < 16; off <<= 1) m = fmaxf(m, __shfl_xor(m, off));
    float ex = __expf(a - m);
    float sum = ex;
#pragma unroll
    for (int off = 1; off < 16; off <<= 1) sum += __shfl_xor(sum, off);
    float r = a - m - __logf(sum);
    if (sub == 0) out[(size_t)node * NC + c] = r;
}

// ---------------- launch ----------------

extern "C" void kernel_launch(void* const* d_in, const int* in_sizes, int n_in,
                              void* d_out, int out_size, void* d_ws, size_t ws_size,
                              hipStream_t stream) {
    const float* x  = (const float*)d_in[0];
    const float* W1 = (const float*)d_in[1];
    const float* b1 = (const float*)d_in[2];
    const float* W2 = (const float*)d_in[3];
    const float* b2 = (const float*)d_in[4];
    const float* ew = (const float*)d_in[5];
    const int* src  = (const int*)d_in[6];
    const int* dst  = (const int*)d_in[7];
    float* out = (float*)d_out;

    char* ws = (char*)d_ws;
    unsigned char* h0q = (unsigned char*)(ws + 0);  // NN*NH = 12,800,000 (fp8)
    bf16*  g       = (bf16*)(ws + 12800000);       // NN*NC*2 = 3,200,000
    int*   row_off = (int*)(ws + 16000000);        // (NN+1)*4 = 400,004
    int*   bucket_cursor = (int*)(ws + 16400016);  // 1,564
    int*   bucket_base   = (int*)(ws + 16401584);  // 1,568
    int2*  edges   = (int2*)(ws + 16403168);       // EE*8 + 256 pad = 25,600,256
    bf16*  W1T     = (bf16*)(ws + 42003424);       // 65,536
    int2*  staged  = (int2*)(ws + 42068960);       // NBKT*BCAP*8 = 30,028,800
    // NOTE: staged no longer aliases h0q -- gemm1 (writes h0q) now runs
    // concurrently with sort (reads staged). End of ws use: 72,097,760.

    // CSR build front half + weight convert
    k_init<<<1, 512, 0, stream>>>(bucket_cursor, edges);
    k_cvtW1<<<(NF * NH) / 256, 256, 0, stream>>>(W1, W1T);
    k_bucket<<<(EE + CHUNK - 1) / CHUNK, 512, 0, stream>>>(src, dst, ew, bucket_cursor, staged);
    k_bscan<<<1, 512, 0, stream>>>(bucket_cursor, bucket_base, row_off);

    // sort || gemm1 (independent; fused for overlap): 391 + 782 = 1173 blocks
    k_sortgemm1<<<1173, 512, 0, stream>>>(staged, bucket_cursor, bucket_base,
                                          row_off, edges, x, W1T, h0q);

    // layer 1 spmm + layer 2 dense (fused)
    k_spmm1g<<<NN / 4, 256, 0, stream>>>(row_off, edges, h0q, b1, W2, g);

    // layer 2 spmm + log_softmax
    k_spmm2<<<NN / 4, 256, 0, stream>>>(row_off, edges, g, b2, out);
}